// Round 7
// baseline (214.717 us; speedup 1.0000x reference)
//
#include <hip/hip_runtime.h>
#include <cstddef>

// Problem constants (B=4, S=2048, D=256, H=8, dh=32, d_ff=512), fp32 in/out.
constexpr int kB   = 4;
constexpr int kS   = 2048;
constexpr int kD   = 256;
constexpr int kH   = 8;
constexpr int kDH  = 32;
constexpr int kDFF = 512;
constexpr int kM   = kB * kS;   // 8192 token rows
constexpr float kEps = 1e-5f;
// 1/sqrt(32) * log2(e): scores pre-scaled so softmax uses exp2 directly.
constexpr float kScaleL2E = 0.17677669529663687f * 1.4426950408889634f;

typedef float f32x4  __attribute__((ext_vector_type(4)));
typedef short bf16x8 __attribute__((ext_vector_type(8)));
typedef unsigned short u16;
typedef unsigned int   u32;

// fp32 -> bf16 round-to-nearest-even
__device__ inline u16 f2bf(float x) {
    union { float f; unsigned u; } c; c.f = x;
    const unsigned r = c.u + 0x7fffu + ((c.u >> 16) & 1u);
    return (u16)(r >> 16);
}

// pack two fp32 -> two bf16 (truncation) in ONE v_perm_b32.
__device__ inline u32 pk_trunc(float lo, float hi) {
    union { float f; u32 u; } a, b; a.f = lo; b.f = hi;
    return __builtin_amdgcn_perm(b.u, a.u, 0x07060302u);
}

// ---------------------------------------------------------------------------
// Fused bf16 MFMA NT GEMM: C = A @ W.T (+bias, epilogue variants).
//  - W arrives fp32 and is cast to bf16 while staging to LDS (no cast pass).
//  - If LNA: A arrives fp32; each block LayerNorm-normalizes its 64 rows
//    (wave-per-row shuffle reduce, K = D = full row) into an LDS A-tile; the
//    K-loop reads A from LDS. Else A is bf16 and read direct from global.
//  - Single barrier after staging; K-loop barrier-free.
// LDS strides 260/516 u16 (dword row-coeff 2 mod 32 -> 2-way bank aliasing,
// free). Tile 64(M) x NT(N), 4 waves, wave w owns rows [m0+16w,+16).
// OUTMODE: 0 = fp32 out (+RES), 1 = SiLU->bf16, 2 = QKV split:
//   Qb[bh][s][dh] (pre-scaled kScaleL2E), Kb[bh][s][dh],
//   Vp = pi-permuted V: s' = (s&~63)|((s&15)*4+((s>>4)&3)), [bh][s'/8][dh][8].
// ---------------------------------------------------------------------------
template<int NT, int OUTMODE, bool RES, int KTOT, bool LNA>
__global__ __launch_bounds__(256)
void gemm_fused(const void* __restrict__ Ain, const float* __restrict__ Wf,
                const float* __restrict__ bias,
                const float* __restrict__ lng, const float* __restrict__ lnb,
                const float* __restrict__ res,
                float* __restrict__ Cf, u16* __restrict__ Cb,
                u16* __restrict__ KbP, u16* __restrict__ VtP, int N)
{
    constexpr int BSTR = KTOT + 4;                 // u16 stride, 8B-aligned rows
    __shared__ u16 Bs[NT * BSTR];
    __shared__ u16 As[LNA ? 64 * 260 : 1];
    const int tid  = threadIdx.x;
    const int wave = tid >> 6;
    const int lane = tid & 63;
    const int quad = lane >> 4;
    const int l16  = lane & 15;
    const int m0 = blockIdx.x * 64;
    const int n0 = blockIdx.y * NT;

    // ---- stage W[n0:n0+NT, :] fp32 -> bf16 LDS (once) ----
    {
        constexpr int TPR = 256 / NT;              // chunks per row
        constexpr int CH  = KTOT / TPR;            // floats per thread
        const int srow = tid % NT;
        const int sci  = tid / NT;
        const float* wsrc = &Wf[(size_t)(n0 + srow) * KTOT + sci * CH];
        u16* wdst = &Bs[srow * BSTR + sci * CH];
        #pragma unroll
        for (int t = 0; t < CH / 4; ++t) {
            const float4 wv = *(const float4*)&wsrc[t * 4];
            *(ushort4*)&wdst[t * 4] = make_ushort4(
                f2bf(wv.x), f2bf(wv.y), f2bf(wv.z), f2bf(wv.w));
        }
    }

    // ---- if LNA: LayerNorm 64 A-rows into LDS (wave-per-row) ----
    if constexpr (LNA) {
        const float* Af = (const float*)Ain;
        const float4 g4 = *(const float4*)&lng[lane * 4];
        const float4 b4 = *(const float4*)&lnb[lane * 4];
        #pragma unroll 4
        for (int rr = 0; rr < 16; ++rr) {
            const int row = m0 + wave * 16 + rr;
            const float4 v = *(const float4*)&Af[(size_t)row * kD + lane * 4];
            float s1 = (v.x + v.y) + (v.z + v.w);
            float s2 = (v.x * v.x + v.y * v.y) + (v.z * v.z + v.w * v.w);
            #pragma unroll
            for (int off = 1; off < 64; off <<= 1) {
                s1 += __shfl_xor(s1, off);
                s2 += __shfl_xor(s2, off);
            }
            const float mu  = s1 * (1.0f / kD);
            const float var = s2 * (1.0f / kD) - mu * mu;
            const float inv = rsqrtf(var + kEps);
            *(ushort4*)&As[(wave * 16 + rr) * 260 + lane * 4] = make_ushort4(
                f2bf((v.x - mu) * inv * g4.x + b4.x),
                f2bf((v.y - mu) * inv * g4.y + b4.y),
                f2bf((v.z - mu) * inv * g4.z + b4.z),
                f2bf((v.w - mu) * inv * g4.w + b4.w));
        }
    }
    __syncthreads();

    // ---- K-loop (barrier-free) ----
    f32x4 acc[NT / 16];
    #pragma unroll
    for (int ni = 0; ni < NT / 16; ++ni) acc[ni] = {0.f, 0.f, 0.f, 0.f};

    const u16* Ab = (const u16*)Ain;
    #pragma unroll 4
    for (int k0 = 0; k0 < KTOT; k0 += 32) {
        bf16x8 a;
        if constexpr (LNA)
            a = *(const bf16x8*)&As[(wave * 16 + l16) * 260 + k0 + quad * 8];
        else
            a = *(const bf16x8*)&Ab[(size_t)(m0 + wave * 16 + l16) * KTOT + k0 + quad * 8];
        #pragma unroll
        for (int ni = 0; ni < NT / 16; ++ni) {
            const bf16x8 bf = *(const bf16x8*)&Bs[(ni * 16 + l16) * BSTR + k0 + quad * 8];
            acc[ni] = __builtin_amdgcn_mfma_f32_16x16x32_bf16(a, bf, acc[ni], 0, 0, 0);
        }
    }

    // ---- epilogue ----
    float bias_v[NT / 16];
    #pragma unroll
    for (int ni = 0; ni < NT / 16; ++ni) bias_v[ni] = bias[n0 + ni * 16 + l16];

    #pragma unroll
    for (int ni = 0; ni < NT / 16; ++ni) {
        #pragma unroll
        for (int r = 0; r < 4; ++r) {
            const int m = m0 + wave * 16 + quad * 4 + r;
            float v = acc[ni][r] + bias_v[ni];
            if (OUTMODE == 0) {
                const int n = n0 + ni * 16 + l16;
                if (RES) v += res[(size_t)m * N + n];
                Cf[(size_t)m * N + n] = v;
            } else if (OUTMODE == 1) {
                const int n = n0 + ni * 16 + l16;
                v = v / (1.0f + __expf(-v));
                Cb[(size_t)m * N + n] = f2bf(v);
            } else {
                const int rgn = n0 >> 8;               // 0=Q 1=K 2=V
                const int nl  = (n0 & 255) + ni * 16 + l16;
                const int hh  = nl >> 5, dh = nl & 31;
                const int bb  = m >> 11, s = m & (kS - 1);
                const int bh  = bb * kH + hh;
                if (rgn == 0)
                    Cb[((size_t)bh * kS + s) * kDH + dh] = f2bf(v * kScaleL2E);
                else if (rgn == 1)
                    KbP[((size_t)bh * kS + s) * kDH + dh] = f2bf(v);
                else {
                    const int sp = (s & ~63) | (((s & 15) << 2) | ((s >> 4) & 3));
                    VtP[(((size_t)bh * (kS / 8) + (sp >> 3)) * kDH + dh) * 8 + (sp & 7)] = f2bf(v);
                }
            }
        }
    }
}

// ---------------------------------------------------------------------------
// MFMA flash attention (unchanged from R6): 32 queries/wave, 2-way key split,
// pi-permuted P/V, no-max online softmax, additive combine via LDS.
// Grid (32, 8, 4) = 1024 blocks.
// ---------------------------------------------------------------------------
constexpr int kPStrU = 72;   // P row stride in u16 (144 B = 16B-aligned rows)

__global__ __launch_bounds__(256, 4)
void attn_kernel(const u16* __restrict__ Qb, const u16* __restrict__ Kb,
                 const u16* __restrict__ Vp, u16* __restrict__ ctx)
{
    __shared__ __align__(16) u16 pbuf[4][32 * kPStrU];   // 18432 B; aliased later
    const int tid  = threadIdx.x;
    const int wave = tid >> 6;
    const int lane = tid & 63;
    const int quad = lane >> 4;
    const int l16  = lane & 15;
    const int h = blockIdx.y;
    const int b = blockIdx.z;
    const int bh = b * kH + h;
    const int qsub = wave >> 1;
    const int half = wave & 1;
    const int q0 = blockIdx.x * 64 + qsub * 32;

    bf16x8 aq[2];
    aq[0] = *(const bf16x8*)&Qb[((size_t)bh * kS + q0 + l16) * kDH + quad * 8];
    aq[1] = *(const bf16x8*)&Qb[((size_t)bh * kS + q0 + 16 + l16) * kDH + quad * 8];

    const u16* Kbase = Kb + (size_t)bh * kS * kDH;
    const u16* Vbase = Vp + (size_t)bh * kS * kDH;
    u16* pw = pbuf[wave];

    f32x4 O[2][2] = {};
    f32x4 lp[2] = {};
    const f32x4 zz = {0.f, 0.f, 0.f, 0.f};

    const int kbeg = half * (kS / 2);
    #pragma unroll 1
    for (int kt = kbeg; kt < kbeg + kS / 2; kt += 64) {
        bf16x8 kf[4];
        #pragma unroll
        for (int kg = 0; kg < 4; ++kg)
            kf[kg] = *(const bf16x8*)
                &Kbase[(size_t)(kt + kg * 16 + l16) * kDH + quad * 8];
        bf16x8 vf[2][2];
        #pragma unroll
        for (int ks = 0; ks < 2; ++ks)
            #pragma unroll
            for (int nf = 0; nf < 2; ++nf)
                vf[ks][nf] = *(const bf16x8*)
                    &Vbase[(size_t)((((kt + ks * 32 + quad * 8) >> 3) * kDH
                                     + nf * 16 + l16) << 3)];

        #pragma unroll
        for (int qb = 0; qb < 2; ++qb) {
            f32x4 S[4];
            #pragma unroll
            for (int kg = 0; kg < 4; ++kg)
                S[kg] = __builtin_amdgcn_mfma_f32_16x16x32_bf16(aq[qb], kf[kg], zz, 0, 0, 0);
            #pragma unroll
            for (int r = 0; r < 4; ++r) {
                const float e0 = exp2f(S[0][r]);
                const float e1 = exp2f(S[1][r]);
                const float e2 = exp2f(S[2][r]);
                const float e3 = exp2f(S[3][r]);
                lp[qb][r] += (e0 + e1) + (e2 + e3);
                uint2 pk;
                pk.x = pk_trunc(e0, e1);
                pk.y = pk_trunc(e2, e3);
                *(uint2*)&pw[(qb * 16 + quad * 4 + r) * kPStrU + l16 * 4] = pk;
            }
        }

        #pragma unroll
        for (int qb = 0; qb < 2; ++qb)
            #pragma unroll
            for (int ks = 0; ks < 2; ++ks) {
                const bf16x8 pA = *(const bf16x8*)
                    &pw[(qb * 16 + l16) * kPStrU + ks * 32 + quad * 8];
                O[qb][0] = __builtin_amdgcn_mfma_f32_16x16x32_bf16(pA, vf[ks][0], O[qb][0], 0, 0, 0);
                O[qb][1] = __builtin_amdgcn_mfma_f32_16x16x32_bf16(pA, vf[ks][1], O[qb][1], 0, 0, 0);
            }
    }

    #pragma unroll
    for (int off = 1; off < 16; off <<= 1)
        #pragma unroll
        for (int qb = 0; qb < 2; ++qb)
            #pragma unroll
            for (int r = 0; r < 4; ++r)
                lp[qb][r] += __shfl_xor(lp[qb][r], off);

    __syncthreads();
    float* cb = (float*)&pbuf[0][0] + qsub * (32 * 33);
    if (half == 1) {
        #pragma unroll
        for (int qb = 0; qb < 2; ++qb)
            #pragma unroll
            for (int r = 0; r < 4; ++r) {
                const int row = qb * 16 + quad * 4 + r;
                cb[row * 33 + l16]      = O[qb][0][r];
                cb[row * 33 + 16 + l16] = O[qb][1][r];
                if (l16 == 0) cb[row * 33 + 32] = lp[qb][r];
            }
    }
    __syncthreads();
    if (half == 0) {
        #pragma unroll
        for (int qb = 0; qb < 2; ++qb)
            #pragma unroll
            for (int r = 0; r < 4; ++r) {
                const int row = qb * 16 + quad * 4 + r;
                const float l   = lp[qb][r] + cb[row * 33 + 32];
                const float inv = 1.0f / l;
                const float o0 = O[qb][0][r] + cb[row * 33 + l16];
                const float o1 = O[qb][1][r] + cb[row * 33 + 16 + l16];
                const int q = q0 + row;
                u16* crow = ctx + ((size_t)(b * kS + q)) * kD + h * kDH;
                crow[l16]      = f2bf(o0 * inv);
                crow[16 + l16] = f2bf(o1 * inv);
            }
    }
}

// ---------------------------------------------------------------------------
// 5 launches: qkv(+LN1) -> attn -> proj(+res) -> ffn1(+LN2+SiLU) -> ffn2(+res)
// Workspace (bytes):
//   [ 0M, 4M)  Qb   : bf16  -- after attn, [0,8M) reused as h (bf16)
//   [ 4M, 8M)  Kb   : bf16
//   [ 8M,12M)  Vp   : bf16 (pi-permuted, chunked)
//   [12M,16M)  ctx  : bf16
// ---------------------------------------------------------------------------
extern "C" void kernel_launch(void* const* d_in, const int* in_sizes, int n_in,
                              void* d_out, int out_size, void* d_ws, size_t ws_size,
                              hipStream_t stream)
{
    const float* x      = (const float*)d_in[0];
    const float* ln1_g  = (const float*)d_in[1];
    const float* ln1_b  = (const float*)d_in[2];
    const float* w_qkv  = (const float*)d_in[3];
    const float* b_qkv  = (const float*)d_in[4];
    const float* w_proj = (const float*)d_in[5];
    const float* b_proj = (const float*)d_in[6];
    const float* ln2_g  = (const float*)d_in[7];
    const float* ln2_b  = (const float*)d_in[8];
    const float* w1     = (const float*)d_in[9];
    const float* b1     = (const float*)d_in[10];
    const float* w2     = (const float*)d_in[11];
    const float* b2     = (const float*)d_in[12];
    float* out = (float*)d_out;

    char* ws = (char*)d_ws;
    u16* Qb  = (u16*)ws;
    u16* Kb  = (u16*)(ws + ((size_t)4  << 20));
    u16* Vp  = (u16*)(ws + ((size_t)8  << 20));
    u16* ctx = (u16*)(ws + ((size_t)12 << 20));
    u16* h   = (u16*)ws;                     // aliases Qb/Kb (dead after attn)

    const dim3 blk(256);

    // 1) Qb/Kb/Vp = bf16(LN1(x) @ w_qkv.T + b_qkv), Q pre-scaled, V permuted
    gemm_fused<64, 2, false, 256, true><<<dim3(kM / 64, 12), blk, 0, stream>>>(
        x, w_qkv, b_qkv, ln1_g, ln1_b, nullptr,
        nullptr, Qb, Kb, Vp, 0);
    // 2) ctx = attention
    attn_kernel<<<dim3(kS / 64, kH, kB), blk, 0, stream>>>(Qb, Kb, Vp, ctx);
    // 3) out = x + ctx @ w_proj.T + b_proj   (fp32)
    gemm_fused<32, 0, true, 256, false><<<dim3(kM / 64, kD / 32), blk, 0, stream>>>(
        ctx, w_proj, b_proj, nullptr, nullptr, x,
        out, nullptr, nullptr, nullptr, kD);
    // 4) h = bf16(silu(LN2(out) @ w1.T + b1))
    gemm_fused<64, 1, false, 256, true><<<dim3(kM / 64, kDFF / 64), blk, 0, stream>>>(
        out, w1, b1, ln2_g, ln2_b, nullptr,
        nullptr, h, nullptr, nullptr, kDFF);
    // 5) out = out + h @ w2.T + b2   (fp32, K=512)
    gemm_fused<32, 0, true, 512, false><<<dim3(kM / 64, kD / 32), blk, 0, stream>>>(
        h, w2, b2, nullptr, nullptr, out,
        out, nullptr, nullptr, nullptr, kD);
}